// Round 15
// baseline (233.469 us; speedup 1.0000x reference)
//
#include <hip/hip_runtime.h>
#include <hip/hip_bf16.h>
#include <math.h>

#define BB 256
#define TT 50
#define VV 100000
#define EMB 64
#define KBD 64
#define HH 128
#define NF 10
#define OUTD 64
#define G3H 384
#define NTILE 6250   // VV/16
#define DSTR 16      // denom stride (floats)
#define NSY 240      // Sy blocks (folded into k_uty launch)

typedef __attribute__((ext_vector_type(8))) short sh8;
typedef __attribute__((ext_vector_type(4))) short sh4;
typedef __attribute__((ext_vector_type(4))) float f32x4;

__device__ __forceinline__ float frcp(float x){ return __builtin_amdgcn_rcpf(x); }
__device__ __forceinline__ float sigm(float x){ return frcp(1.0f+__expf(-x)); }
__device__ __forceinline__ float tanhf_(float x){ return 1.0f - 2.0f*frcp(__expf(2.0f*x)+1.0f); }
__device__ __forceinline__ short f2bs(float f){ __hip_bfloat16 h=__float2bfloat16(f); return *reinterpret_cast<short*>(&h); }
__device__ __forceinline__ sh8 ldfrag(const float* p){
  float4 a = *(const float4*)p; float4 b = *(const float4*)(p+4);
  sh8 v;
  v[0]=f2bs(a.x); v[1]=f2bs(a.y); v[2]=f2bs(a.z); v[3]=f2bs(a.w);
  v[4]=f2bs(b.x); v[5]=f2bs(b.y); v[6]=f2bs(b.z); v[7]=f2bs(b.w);
  return v;
}
__device__ __forceinline__ sh8 ldfrag_s(const float* p, float s){
  float4 a = *(const float4*)p; float4 b = *(const float4*)(p+4);
  sh8 v;
  v[0]=f2bs(a.x*s); v[1]=f2bs(a.y*s); v[2]=f2bs(a.z*s); v[3]=f2bs(a.w*s);
  v[4]=f2bs(b.x*s); v[5]=f2bs(b.y*s); v[6]=f2bs(b.z*s); v[7]=f2bs(b.w*s);
  return v;
}
// LDS-only barrier (no vmcnt drain)
__device__ __forceinline__ void barrier_lds(){
  asm volatile("s_waitcnt lgkmcnt(0)" ::: "memory");
  __builtin_amdgcn_sched_barrier(0);
  __builtin_amdgcn_s_barrier();
  __builtin_amdgcn_sched_barrier(0);
}

// ====== k_pre: gi/ea via MFMA (400 blocks); block 0 zeros denom + ybf32 ======
#define PREP 32
__global__ __launch_bounds__(512) void k_pre(
    const int* __restrict__ X, const float* __restrict__ E, const float* __restrict__ KBE,
    const float* __restrict__ Wih, const float* __restrict__ bih, const float* __restrict__ bhh,
    const float* __restrict__ eaW, const float* __restrict__ eab,
    float* __restrict__ gi_pre, float* __restrict__ ea_pre,
    __hip_bfloat16* __restrict__ ea_bfT, float* __restrict__ denom,
    float* __restrict__ ybf32) {
  const int tid = threadIdx.x;
  const int w = tid>>6, l = tid&63, r16 = l&15, g4 = l>>4;

  if (blockIdx.x == 0){
    for (int i=tid;i<BB*DSTR;i+=512) denom[i]=0.f;
    for (int i=tid;i<BB*OUTD;i+=512) ybf32[i]=0.f;
  }
  __shared__ float xeL[PREP][68];
  __shared__ float kbL[PREP][68];
  int base = blockIdx.x * PREP;
  for (int i=tid; i<PREP*EMB; i+=512){
    int p=i>>6, k=i&63; int x = X[base+p];
    xeL[p][k] = x ? E[(size_t)x*EMB+k] : 0.0f;
    kbL[p][k] = x ? KBE[(size_t)x*KBD+k] : 0.0f;
  }
  __syncthreads();

  const int m = w>>2, nq = w&3;
  sh8 axe[2], akb[2];
  #pragma unroll
  for (int f=0;f<2;f++){
    axe[f] = ldfrag(&xeL[m*16 + r16][f*32 + g4*8]);
    akb[f] = ldfrag(&kbL[m*16 + r16][f*32 + g4*8]);
  }
  #pragma unroll
  for (int i=0;i<6;i++){
    int nt = nq*6 + i;
    int j = nt*16 + r16;
    sh8 bf0 = ldfrag(Wih + (size_t)j*EMB + g4*8);
    sh8 bf1 = ldfrag(Wih + (size_t)j*EMB + 32 + g4*8);
    f32x4 acc = {0.f,0.f,0.f,0.f};
    acc = __builtin_amdgcn_mfma_f32_16x16x32_bf16(axe[0], bf0, acc,0,0,0);
    acc = __builtin_amdgcn_mfma_f32_16x16x32_bf16(axe[1], bf1, acc,0,0,0);
    float bj = bih[j] + (j < 2*HH ? bhh[j] : 0.0f);
    #pragma unroll
    for (int r=0;r<4;r++){
      int pair = base + m*16 + g4*4 + r;
      gi_pre[(size_t)pair*G3H + j] = acc[r] + bj;
    }
  }
  {
    int d = nq*16 + r16;
    sh8 bf0 = ldfrag(eaW + (size_t)d*KBD + g4*8);
    sh8 bf1 = ldfrag(eaW + (size_t)d*KBD + 32 + g4*8);
    f32x4 acc = {0.f,0.f,0.f,0.f};
    acc = __builtin_amdgcn_mfma_f32_16x16x32_bf16(akb[0], bf0, acc,0,0,0);
    acc = __builtin_amdgcn_mfma_f32_16x16x32_bf16(akb[1], bf1, acc,0,0,0);
    float bd = eab[d];
    #pragma unroll
    for (int r=0;r<4;r++){
      int pair = base + m*16 + g4*4 + r;
      float v = tanhf(acc[r] + bd);
      ea_pre[(size_t)pair*KBD + d] = v;
      int bb = pair/TT, tt = pair - bb*TT;
      ea_bfT[((size_t)bb*64 + d)*64 + tt] = __float2bfloat16(v);
    }
  }
}

// ====== k_scanh: blocks 0-15 = h-recurrence (4 waves); 16-79 = gram ======
__global__ __launch_bounds__(256,2) void k_scanh(
    const float* __restrict__ gi_pre,
    const float* __restrict__ Whh, const float* __restrict__ bhh,
    const float* __restrict__ ea_pre, const float* __restrict__ rmat,
    float* __restrict__ Gg, float* __restrict__ Pg,
    __hip_bfloat16* __restrict__ h_stream) {
  const int tid = threadIdx.x;
  const int w = tid>>6, l = tid&63, r16 = l&15, g4 = l>>4;

  if (blockIdx.x >= 16) {
    const int b = (blockIdx.x-16)*4 + w;
    sh8 aa[4][2];
    #pragma unroll
    for (int i=0;i<4;i++){
      int row = i*16 + r16; if (row > TT-1) row = TT-1;
      #pragma unroll
      for (int f=0;f<2;f++)
        aa[i][f] = ldfrag(ea_pre + ((size_t)b*TT + row)*KBD + f*32 + g4*8);
    }
    sh8 rmB[2];
    #pragma unroll
    for (int f=0;f<2;f++){
      sh8 z = {0,0,0,0,0,0,0,0};
      if (r16 < NF) z = ldfrag(rmat + (size_t)r16*KBD + f*32 + g4*8);
      rmB[f] = z;
    }
    float* Gb = Gg + ((size_t)b<<12);
    #pragma unroll
    for (int i=0;i<4;i++){
      #pragma unroll
      for (int j=0;j<4;j++){
        f32x4 acc={0.f,0.f,0.f,0.f};
        #pragma unroll
        for (int f=0;f<2;f++) acc = __builtin_amdgcn_mfma_f32_16x16x32_bf16(aa[i][f], aa[j][f], acc,0,0,0);
        #pragma unroll
        for (int r=0;r<4;r++) Gb[(i*16+g4*4+r)*64 + j*16+r16] = acc[r];
      }
      f32x4 accp={0.f,0.f,0.f,0.f};
      #pragma unroll
      for (int f=0;f<2;f++) accp = __builtin_amdgcn_mfma_f32_16x16x32_bf16(aa[i][f], rmB[f], accp,0,0,0);
      #pragma unroll
      for (int r=0;r<4;r++) Pg[((size_t)b<<10) + (i*16+g4*4+r)*16 + r16] = accp[r];
    }
    return;
  }

  __shared__ __hip_bfloat16 hcat[2][16][128];
  __builtin_amdgcn_s_setprio(1);
  const int b = blockIdx.x;
  const int b0 = b*16;
  for (int i=tid;i<2*16*128;i+=256) ((short*)hcat)[i]=0;
  __syncthreads();
  const int swz = (r16&7)<<4;

  sh8 whhF[2][3][4];
  #pragma unroll
  for (int t=0;t<2;t++)
    #pragma unroll
    for (int g=0;g<3;g++){
      int chain = (w + 4*t) + 8*g;
      #pragma unroll
      for (int f=0;f<4;f++)
        whhF[t][g][f] = ldfrag(Whh + (size_t)(chain*16 + r16)*HH + f*32 + g4*8);
    }
  float4 bhn[2];
  bhn[0] = *(const float4*)(bhh + 2*HH + w*16 + g4*4);
  bhn[1] = *(const float4*)(bhh + 2*HH + (w+4)*16 + g4*4);
  float h_old[2][4] = {{0.f,0.f,0.f,0.f},{0.f,0.f,0.f,0.f}};
  const float* gi_row = gi_pre + (size_t)(b0+r16)*TT*G3H;
  __hip_bfloat16* hsb = h_stream + (size_t)b*TT*16*HH;

  int cur = 0;
  auto stepfn = [&](int s, float4 (&gi)[2][3], int cu){
    const char* hrow = (const char*)&hcat[cu][r16][0];
    sh8 hb[4];
    #pragma unroll
    for (int f=0;f<4;f++)
      hb[f] = *(const sh8*)(hrow + ((f*64 + g4*16) ^ swz));
    f32x4 aR[2], aZ[2], aN[2];
    #pragma unroll
    for (int t=0;t<2;t++){ f32x4 z={0.f,0.f,0.f,0.f}; aR[t]=z; aZ[t]=z; aN[t]=z; }
    #pragma unroll
    for (int f=0;f<4;f++){
      #pragma unroll
      for (int t=0;t<2;t++){
        aR[t] = __builtin_amdgcn_mfma_f32_16x16x32_bf16(whhF[t][0][f], hb[f], aR[t],0,0,0);
        aZ[t] = __builtin_amdgcn_mfma_f32_16x16x32_bf16(whhF[t][1][f], hb[f], aZ[t],0,0,0);
        aN[t] = __builtin_amdgcn_mfma_f32_16x16x32_bf16(whhF[t][2][f], hb[f], aN[t],0,0,0);
      }
    }
    char* hwrow = (char*)&hcat[cu^1][r16][0];
    #pragma unroll
    for (int t=0;t<2;t++){
      sh4 hp;
      #pragma unroll
      for (int r=0;r<4;r++){
        float rr = sigm(gi[t][0][r] + aR[t][r]);
        float zz = sigm(gi[t][1][r] + aZ[t][r]);
        float nn = tanhf_(gi[t][2][r] + rr*(aN[t][r] + bhn[t][r]));
        h_old[t][r] = (1.f-zz)*nn + zz*h_old[t][r];
        hp[r] = f2bs(h_old[t][r]);
      }
      *(sh4*)(hwrow + (((w+4*t)*32 + g4*8) ^ swz)) = hp;
      *(sh4*)(hsb + ((size_t)s*16 + r16)*HH + (w+4*t)*16 + g4*4) = hp;
    }
    barrier_lds();
  };

  float4 gA[2][3], gB[2][3];
  #pragma unroll
  for (int t=0;t<2;t++)
    #pragma unroll
    for (int g=0;g<3;g++)
      gA[t][g] = *(const float4*)(gi_row + g*128 + (w+4*t)*16 + g4*4);

  for (int s=0;s<TT;s+=2){
    {
      int sg = s+1;
      #pragma unroll
      for (int t=0;t<2;t++)
        #pragma unroll
        for (int g=0;g<3;g++)
          gB[t][g] = *(const float4*)(gi_row + (size_t)sg*G3H + g*128 + (w+4*t)*16 + g4*4);
      stepfn(s, gA, cur);
      cur ^= 1;
    }
    {
      int sg = (s+2<TT)? s+2 : TT-1;
      #pragma unroll
      for (int t=0;t<2;t++)
        #pragma unroll
        for (int g=0;g<3;g++)
          gA[t][g] = *(const float4*)(gi_row + (size_t)sg*G3H + g*128 + (w+4*t)*16 + g4*4);
      stepfn(s+1, gB, cur);
      cur ^= 1;
    }
  }
}

// ====== k_mnac: U+softmax (MFMA) + gate recurrence + AC GEMM, one b per block ======
__global__ __launch_bounds__(640) void k_mnac(
    const float* __restrict__ Gg, const float* __restrict__ Pg,
    const float* __restrict__ rmat,
    const __hip_bfloat16* __restrict__ h_stream,
    const float* __restrict__ uW, const float* __restrict__ ub,
    const __hip_bfloat16* __restrict__ ea_bfT,
    __hip_bfloat16* __restrict__ ac_pre) {
  __shared__ __hip_bfloat16 U_sh[64][72];
  __shared__ float aw_sh[64*16];
  __shared__ float AagL[64*52];
  __shared__ float BagL[64*16];
  const int tid = threadIdx.x;
  const int n = tid>>6, l = tid&63, r16 = l&15, g4 = l>>4;
  const int b = blockIdx.x;
  for (int i=tid;i<64*52;i+=640) AagL[i]=0.f;
  for (int i=tid;i<64*16;i+=640) BagL[i]=0.f;

  const __hip_bfloat16* hsb = h_stream + ((size_t)(b>>4)*TT)*16*HH + (size_t)(b&15)*HH;

  // ---- U = tanh(uW.h + ub) for all 50 t (16 tile-combos over 10 waves) ----
  #pragma unroll
  for (int cc=0; cc<2; cc++){
    int c = n + cc*10;
    if (c < 16){
      int mi = c>>2, ni = c&3;
      int t = mi*16 + r16; int tt = (t<TT)? t : TT-1;
      sh8 hfr[4], wfr[4];
      #pragma unroll
      for (int f=0;f<4;f++){
        hfr[f] = *(const sh8*)(hsb + (size_t)tt*16*HH + f*32 + g4*8);
        wfr[f] = ldfrag(uW + (size_t)(ni*16+r16)*HH + f*32 + g4*8);
      }
      f32x4 acc = {0.f,0.f,0.f,0.f};
      #pragma unroll
      for (int f=0;f<4;f++)
        acc = __builtin_amdgcn_mfma_f32_16x16x32_bf16(wfr[f], hfr[f], acc,0,0,0);
      float4 ubv = *(const float4*)(ub + ni*16 + g4*4);
      #pragma unroll
      for (int r=0;r<4;r++)
        U_sh[mi*16 + r16][ni*16 + g4*4 + r] = __float2bfloat16(tanhf_(acc[r] + ubv[r]));
    }
  }
  __syncthreads();
  // ---- attention logits + softmax (waves 0-3; wave w = t-tile) ----
  if (n < 4){
    sh8 rmF[2];
    #pragma unroll
    for (int f=0;f<2;f++){
      sh8 z = {0,0,0,0,0,0,0,0};
      if (r16 < NF) z = ldfrag(rmat + (size_t)r16*KBD + f*32 + g4*8);
      rmF[f] = z;
    }
    sh8 uf[2];
    #pragma unroll
    for (int f=0;f<2;f++) uf[f] = *(const sh8*)&U_sh[n*16 + r16][f*32 + g4*8];
    f32x4 al={0.f,0.f,0.f,0.f};
    #pragma unroll
    for (int f=0;f<2;f++) al = __builtin_amdgcn_mfma_f32_16x16x32_bf16(rmF[f], uf[f], al,0,0,0);
    float mx = -1e30f;
    #pragma unroll
    for (int r=0;r<4;r++){ if (g4*4+r < NF) mx = fmaxf(mx, al[r]); }
    mx = fmaxf(mx, __shfl_xor(mx,16));
    mx = fmaxf(mx, __shfl_xor(mx,32));
    float av[4]; float ssum=0.f;
    #pragma unroll
    for (int r=0;r<4;r++){ av[r] = (g4*4+r < NF) ? __expf(al[r]-mx) : 0.f; ssum += av[r]; }
    ssum += __shfl_xor(ssum,16); ssum += __shfl_xor(ssum,32);
    float inv = frcp(ssum);
    #pragma unroll
    for (int r=0;r<4;r++){
      int nn = g4*4+r;
      if (nn < NF) aw_sh[(n*16 + r16)*16 + nn] = av[r]*inv;
    }
  }
  __syncthreads();

  // ---- gate recurrence (10 waves = n) ----
  float rv = rmat[n*KBD + l];
  float R = rv*rv;
  R += __shfl_xor(R,1); R += __shfl_xor(R,2); R += __shfl_xor(R,4);
  R += __shfl_xor(R,8); R += __shfl_xor(R,16); R += __shfl_xor(R,32);

  float Pn = (l<TT)? Pg[((size_t)b<<10) + l*16 + n] : 0.f;
  const float* Gb = Gg + ((size_t)b<<12);
  float Grow = Gb[l];
  float d=0.f, w_=0.f, q=1.f;

  for (int t=0;t<TT;t++){
    int tn = (t+1<TT)? t+1 : TT-1;
    float GrowN = Gb[tn*64 + l];
    float dt = __shfl(d, t);
    float g  = sigm(dt);
    float og = 1.f - g;
    float Pt = __shfl(Pn, t);
    float Ets = Grow + Pt + Pn + R;
    d = og*d + g*Ets;
    w_ = (l==t)? g : w_*og;
    q *= og;
    float awt = aw_sh[t*16 + n];
    if (l < TT) atomicAdd(&AagL[t*52 + l], awt*w_);
    if (l == 0) BagL[t*16 + n] = awt*(1.f - q);
    Grow = GrowN;
  }
  __syncthreads();

  // ---- fused AC GEMM (waves 0-3; wave w owns j-tile w) ----
  if (n < 4){
    const int w = n;
    sh8 a1[4][2], a2[4];
    #pragma unroll
    for (int i=0;i<4;i++){
      int row = i*16 + r16;
      #pragma unroll
      for (int f=0;f<2;f++) a1[i][f] = ldfrag(&AagL[row*52 + f*32 + g4*8]);
      a2[i] = ldfrag(&BagL[row*16 + ((g4*8) & 15)]);
      if (g4 >= 2){ sh8 z={0,0,0,0,0,0,0,0}; a2[i]=z; }
    }
    int j = w;
    sh8 bb1[2];
    #pragma unroll
    for (int f=0;f<2;f++)
      bb1[f] = *(const sh8*)(ea_bfT + ((size_t)b<<12) + (j*16+r16)*64 + f*32 + g4*8);
    sh8 bb2;
    #pragma unroll
    for (int c=0;c<8;c++){
      int k = g4*8 + c;
      bb2[c] = (k<NF)? f2bs(rmat[k*KBD + j*16+r16]) : (short)0;
    }
    #pragma unroll
    for (int i=0;i<4;i++){
      f32x4 acc={0.f,0.f,0.f,0.f};
      #pragma unroll
      for (int f=0;f<2;f++) acc = __builtin_amdgcn_mfma_f32_16x16x32_bf16(a1[i][f], bb1[f], acc,0,0,0);
      acc = __builtin_amdgcn_mfma_f32_16x16x32_bf16(a2[i], bb2, acc,0,0,0);
      #pragma unroll
      for (int r=0;r<4;r++){
        int t = i*16 + g4*4 + r;
        if (t < TT)
          ac_pre[((size_t)t*256 + b)*KBD + j*16 + r16] = __float2bfloat16(acc[r]);
      }
    }
  }
}

// ====== k_uty: blocks 0-799 = Ut+y (atomic ysum); blocks 800-1039 = Sy ======
__global__ __launch_bounds__(512) void k_uty(
    const __hip_bfloat16* __restrict__ h_stream, const __hip_bfloat16* __restrict__ ac_pre,
    const float* __restrict__ u2W, const float* __restrict__ u2b,
    const float* __restrict__ m1W, const float* __restrict__ m1b,
    float* __restrict__ ybf32,
    const float* __restrict__ E, const float* __restrict__ KBE,
    const float* __restrict__ m2W, const float* __restrict__ m2b,
    __hip_bfloat16* __restrict__ Sy) {
  __shared__ __hip_bfloat16 ut_sh[16][136];
  const int tid = threadIdx.x;
  const int w = tid>>6, l = tid&63, r16 = l&15, g4 = l>>4;

  if (blockIdx.x >= 800) {
    // ---------------- Sy path ----------------
    int kof = g4*8;
    sh8 bbf[4][4];
    float bias[4];
    #pragma unroll
    for (int nt=0;nt<4;nt++){
      int o = nt*16 + r16;
      bias[nt] = m2b[o];
      #pragma unroll
      for (int ks=0;ks<4;ks++) bbf[nt][ks] = ldfrag(m2W + o*128 + ks*32 + kof);
    }
    int wid = (blockIdx.x-800)*8 + w;
    for (int tile=wid; tile<NTILE; tile+=NSY*8){
      int v = tile*16 + r16;
      sh8 aa[4];
      const float* ep = E + (size_t)v*EMB + kof;
      const float* kp = KBE + (size_t)v*KBD + kof;
      aa[0] = ldfrag(ep); aa[1] = ldfrag(ep+32);
      aa[2] = ldfrag(kp); aa[3] = ldfrag(kp+32);
      if (v==0){ sh8 z={0,0,0,0,0,0,0,0}; aa[0]=z;aa[1]=z;aa[2]=z;aa[3]=z; }
      f32x4 acc[4];
      #pragma unroll
      for (int nt=0;nt<4;nt++){ f32x4 z={0.f,0.f,0.f,0.f}; acc[nt]=z; }
      #pragma unroll
      for (int nt=0;nt<4;nt++)
        #pragma unroll
        for (int ks=0;ks<4;ks++)
          acc[nt] = __builtin_amdgcn_mfma_f32_16x16x32_bf16(aa[ks],bbf[nt][ks],acc[nt],0,0,0);
      #pragma unroll
      for (int nt=0;nt<4;nt++){
        #pragma unroll
        for (int r=0;r<4;r++){
          int vv = tile*16 + g4*4 + r;
          Sy[(size_t)vv*OUTD + nt*16 + r16] = __float2bfloat16(tanhf_(acc[nt][r] + bias[nt]));
        }
      }
    }
    return;
  }

  const int t = blockIdx.x>>4, btile = blockIdx.x&15;
  const int b0 = btile*16, fb = btile;

  sh8 u2F[6];
  #pragma unroll
  for (int f=0;f<6;f++) u2F[f] = ldfrag(u2W + (size_t)(w*16+r16)*(HH+KBD) + f*32 + g4*8);
  sh8 m1F[4];
  if (w<4){
    #pragma unroll
    for (int f=0;f<4;f++) m1F[f] = ldfrag(m1W + (size_t)(w*16+r16)*HH + f*32 + g4*8);
  }
  float4 u2bv = *(const float4*)(u2b + w*16 + g4*4);

  const __hip_bfloat16* hp = h_stream + (size_t)((fb*TT + t)*16)*HH;
  const __hip_bfloat16* ap = ac_pre + ((size_t)t*256 + b0)*KBD;
  sh8 cb[6];
  #pragma unroll
  for (int f=0;f<4;f++) cb[f] = *(const sh8*)(hp + r16*HH + f*32 + g4*8);
  #pragma unroll
  for (int f=4;f<6;f++) cb[f] = *(const sh8*)(ap + r16*KBD + (f-4)*32 + g4*8);
  f32x4 at={0.f,0.f,0.f,0.f};
  #pragma unroll
  for (int f=0;f<6;f++) at = __builtin_amdgcn_mfma_f32_16x16x32_bf16(u2F[f], cb[f], at,0,0,0);
  sh4 tp;
  #pragma unroll
  for (int r=0;r<4;r++) tp[r] = f2bs(tanhf_(at[r] + u2bv[r]));
  *(sh4*)&ut_sh[r16][w*16+g4*4] = tp;
  __syncthreads();
  if (w<4){
    float4 m1bv = *(const float4*)(m1b + w*16 + g4*4);
    sh8 tb[4];
    #pragma unroll
    for (int f=0;f<4;f++) tb[f] = *(const sh8*)&ut_sh[r16][f*32+g4*8];
    f32x4 ay={0.f,0.f,0.f,0.f};
    #pragma unroll
    for (int f=0;f<4;f++) ay = __builtin_amdgcn_mfma_f32_16x16x32_bf16(m1F[f], tb[f], ay,0,0,0);
    #pragma unroll
    for (int r=0;r<4;r++)
      atomicAdd(&ybf32[(size_t)(b0 + r16)*OUTD + w*16 + g4*4 + r], tanhf_(ay[r] + m1bv[r]));
  }
}

// ---------------- final: s = y @ Sy^T, log_softmax ----------------
__global__ __launch_bounds__(256) void k_logits(
    const float* __restrict__ ybf32, const __hip_bfloat16* __restrict__ Sy,
    float* __restrict__ denom, float* __restrict__ out, int pass) {
  __shared__ float dsum[64];
  int lane = threadIdx.x & 63;
  int w = threadIdx.x >> 6;
  int r16 = lane & 15, g4 = lane >> 4;
  int kof = g4 * 8;
  int tbase = blockIdx.x * 16 + w * 4;
  const float SC = 1.0f/TT;
  if (pass==0){
    if (threadIdx.x<64) dsum[threadIdx.x]=0.f;
    __syncthreads();
  }
  sh8 b0[4], b1[4];
  #pragma unroll
  for (int i=0;i<4;i++){
    if (tbase + i < NTILE) {
      const __hip_bfloat16* bp = Sy + ((size_t)((tbase+i)*16 + r16))*OUTD + kof;
      b0[i] = *(const sh8*)bp;
      b1[i] = *(const sh8*)(bp + 32);
    } else {
      sh8 z = {0,0,0,0,0,0,0,0};
      b0[i]=z; b1[i]=z;
    }
  }
  int bg0 = blockIdx.y * 4;
  for (int bgi=0; bgi<4; bgi++){
    int bg = bg0 + bgi;
    const float* ap = ybf32 + (size_t)(bg*16 + r16)*OUTD + kof;
    sh8 a0 = ldfrag_s(ap, SC);
    sh8 a1 = ldfrag_s(ap+32, SC);
    if (pass == 0){
      float part[4] = {0.f,0.f,0.f,0.f};
      #pragma unroll
      for (int i=0;i<4;i++){
        if (tbase + i < NTILE){
          f32x4 acc = {0.f,0.f,0.f,0.f};
          acc = __builtin_amdgcn_mfma_f32_16x16x32_bf16(a0,b0[i],acc,0,0,0);
          acc = __builtin_amdgcn_mfma_f32_16x16x32_bf16(a1,b1[i],acc,0,0,0);
          #pragma unroll
          for (int r=0;r<4;r++) part[r] += __expf(acc[r]);
        }
      }
      #pragma unroll
      for (int r=0;r<4;r++){
        float p = part[r];
        p += __shfl_xor(p,1,16); p += __shfl_xor(p,2,16);
        p += __shfl_xor(p,4,16); p += __shfl_xor(p,8,16);
        if (r16==0) atomicAdd(&dsum[bgi*16 + g4*4 + r], p);
      }
    } else {
      float lse[4];
      #pragma unroll
      for (int r=0;r<4;r++) lse[r] = logf(denom[(size_t)(bg*16 + g4*4 + r)*DSTR]);
      #pragma unroll
      for (int i=0;i<4;i++){
        if (tbase + i < NTILE){
          f32x4 acc = {0.f,0.f,0.f,0.f};
          acc = __builtin_amdgcn_mfma_f32_16x16x32_bf16(a0,b0[i],acc,0,0,0);
          acc = __builtin_amdgcn_mfma_f32_16x16x32_bf16(a1,b1[i],acc,0,0,0);
          int vc = (tbase+i)*16 + r16;
          #pragma unroll
          for (int r=0;r<4;r++)
            out[(size_t)(bg*16 + g4*4 + r)*VV + vc] = acc[r] - lse[r];
        }
      }
    }
  }
  if (pass==0){
    __syncthreads();
    if (threadIdx.x<64)
      atomicAdd(&denom[(size_t)(bg0*16 + threadIdx.x)*DSTR], dsum[threadIdx.x]);
  }
}

extern "C" void kernel_launch(void* const* d_in, const int* in_sizes, int n_in,
                              void* d_out, int out_size, void* d_ws, size_t ws_size,
                              hipStream_t stream) {
  const int*   X    = (const int*)  d_in[0];
  const float* E    = (const float*)d_in[1];
  const float* KBE  = (const float*)d_in[2];
  const float* rmat = (const float*)d_in[3];
  const float* Wih  = (const float*)d_in[4];
  const float* Whh  = (const float*)d_in[5];
  const float* bih  = (const float*)d_in[6];
  const float* bhh  = (const float*)d_in[7];
  const float* uW   = (const float*)d_in[8];
  const float* ub   = (const float*)d_in[9];
  const float* eaW  = (const float*)d_in[10];
  const float* eab  = (const float*)d_in[11];
  const float* u2W  = (const float*)d_in[12];
  const float* u2b  = (const float*)d_in[13];
  const float* m1W  = (const float*)d_in[14];
  const float* m1b  = (const float*)d_in[15];
  const float* m2W  = (const float*)d_in[16];
  const float* m2b  = (const float*)d_in[17];
  float* outp = (float*)d_out;

  char* p = (char*)d_ws;
  float* gi_pre = (float*)p;            p += (size_t)BB*TT*G3H*4;
  float* ea_pre = (float*)p;            p += (size_t)BB*TT*KBD*4;
  float* denom  = (float*)p;            p += (size_t)BB*DSTR*4;
  float* ybf32  = (float*)p;            p += (size_t)BB*OUTD*4;
  float* Gg     = (float*)p;            p += (size_t)BB*64*64*4;
  float* Pg     = (float*)p;            p += (size_t)BB*64*16*4;
  __hip_bfloat16* h_stream = (__hip_bfloat16*)p; p += (size_t)16*TT*16*HH*2;
  __hip_bfloat16* ea_bfT = (__hip_bfloat16*)p;   p += (size_t)BB*64*64*2;
  __hip_bfloat16* ac_pre = (__hip_bfloat16*)p;   p += (size_t)BB*TT*KBD*2;
  __hip_bfloat16* Sy     = (__hip_bfloat16*)p;   p += (size_t)VV*OUTD*2;

  k_pre<<<400,512,0,stream>>>(X,E,KBE,Wih,bih,bhh,eaW,eab,gi_pre,ea_pre,ea_bfT,denom,ybf32);
  k_scanh<<<80,256,0,stream>>>(gi_pre,Whh,bhh,ea_pre,rmat,Gg,Pg,h_stream);
  k_mnac<<<256,640,0,stream>>>(Gg,Pg,rmat,h_stream,uW,ub,ea_bfT,ac_pre);
  k_uty<<<800+NSY,512,0,stream>>>(h_stream,ac_pre,u2W,u2b,m1W,m1b,ybf32,
                                  E,KBE,m2W,m2b,Sy);
  dim3 g1((NTILE + 15)/16, 4, 1);
  k_logits<<<g1,256,0,stream>>>(ybf32,Sy,denom,outp,0);
  k_logits<<<g1,256,0,stream>>>(ybf32,Sy,denom,outp,1);
}

// Round 16
// 224.953 us; speedup vs baseline: 1.0379x; 1.0379x over previous
//
#include <hip/hip_runtime.h>
#include <hip/hip_bf16.h>
#include <math.h>

#define BB 256
#define TT 50
#define VV 100000
#define EMB 64
#define KBD 64
#define HH 128
#define NF 10
#define OUTD 64
#define G3H 384
#define NTILE 6250   // VV/16
#define DSTR 16      // denom stride (floats)
#define NSY 240      // Sy blocks (folded into k_uty launch)
#define TCH 4        // t's per k_uty block
#define NUTY (16*13) // 16 btiles x ceil(50/4)=13 tchunks

typedef __attribute__((ext_vector_type(8))) short sh8;
typedef __attribute__((ext_vector_type(4))) short sh4;
typedef __attribute__((ext_vector_type(4))) float f32x4;

__device__ __forceinline__ float frcp(float x){ return __builtin_amdgcn_rcpf(x); }
__device__ __forceinline__ float sigm(float x){ return frcp(1.0f+__expf(-x)); }
__device__ __forceinline__ float tanhf_(float x){ return 1.0f - 2.0f*frcp(__expf(2.0f*x)+1.0f); }
__device__ __forceinline__ short f2bs(float f){ __hip_bfloat16 h=__float2bfloat16(f); return *reinterpret_cast<short*>(&h); }
__device__ __forceinline__ sh8 ldfrag(const float* p){
  float4 a = *(const float4*)p; float4 b = *(const float4*)(p+4);
  sh8 v;
  v[0]=f2bs(a.x); v[1]=f2bs(a.y); v[2]=f2bs(a.z); v[3]=f2bs(a.w);
  v[4]=f2bs(b.x); v[5]=f2bs(b.y); v[6]=f2bs(b.z); v[7]=f2bs(b.w);
  return v;
}
__device__ __forceinline__ sh8 ldfrag_s(const float* p, float s){
  float4 a = *(const float4*)p; float4 b = *(const float4*)(p+4);
  sh8 v;
  v[0]=f2bs(a.x*s); v[1]=f2bs(a.y*s); v[2]=f2bs(a.z*s); v[3]=f2bs(a.w*s);
  v[4]=f2bs(b.x*s); v[5]=f2bs(b.y*s); v[6]=f2bs(b.z*s); v[7]=f2bs(b.w*s);
  return v;
}
// LDS-only barrier (no vmcnt drain)
__device__ __forceinline__ void barrier_lds(){
  asm volatile("s_waitcnt lgkmcnt(0)" ::: "memory");
  __builtin_amdgcn_sched_barrier(0);
  __builtin_amdgcn_s_barrier();
  __builtin_amdgcn_sched_barrier(0);
}

// ====== k_pre: gi/ea via MFMA (400 blocks); block 0 zeros denom + ybf32 ======
#define PREP 32
__global__ __launch_bounds__(512) void k_pre(
    const int* __restrict__ X, const float* __restrict__ E, const float* __restrict__ KBE,
    const float* __restrict__ Wih, const float* __restrict__ bih, const float* __restrict__ bhh,
    const float* __restrict__ eaW, const float* __restrict__ eab,
    float* __restrict__ gi_pre, float* __restrict__ ea_pre,
    __hip_bfloat16* __restrict__ ea_bfT, float* __restrict__ denom,
    float* __restrict__ ybf32) {
  const int tid = threadIdx.x;
  const int w = tid>>6, l = tid&63, r16 = l&15, g4 = l>>4;

  if (blockIdx.x == 0){
    for (int i=tid;i<BB*DSTR;i+=512) denom[i]=0.f;
    for (int i=tid;i<BB*OUTD;i+=512) ybf32[i]=0.f;
  }
  __shared__ float xeL[PREP][68];
  __shared__ float kbL[PREP][68];
  int base = blockIdx.x * PREP;
  for (int i=tid; i<PREP*EMB; i+=512){
    int p=i>>6, k=i&63; int x = X[base+p];
    xeL[p][k] = x ? E[(size_t)x*EMB+k] : 0.0f;
    kbL[p][k] = x ? KBE[(size_t)x*KBD+k] : 0.0f;
  }
  __syncthreads();

  const int m = w>>2, nq = w&3;
  sh8 axe[2], akb[2];
  #pragma unroll
  for (int f=0;f<2;f++){
    axe[f] = ldfrag(&xeL[m*16 + r16][f*32 + g4*8]);
    akb[f] = ldfrag(&kbL[m*16 + r16][f*32 + g4*8]);
  }
  #pragma unroll
  for (int i=0;i<6;i++){
    int nt = nq*6 + i;
    int j = nt*16 + r16;
    sh8 bf0 = ldfrag(Wih + (size_t)j*EMB + g4*8);
    sh8 bf1 = ldfrag(Wih + (size_t)j*EMB + 32 + g4*8);
    f32x4 acc = {0.f,0.f,0.f,0.f};
    acc = __builtin_amdgcn_mfma_f32_16x16x32_bf16(axe[0], bf0, acc,0,0,0);
    acc = __builtin_amdgcn_mfma_f32_16x16x32_bf16(axe[1], bf1, acc,0,0,0);
    float bj = bih[j] + (j < 2*HH ? bhh[j] : 0.0f);
    #pragma unroll
    for (int r=0;r<4;r++){
      int pair = base + m*16 + g4*4 + r;
      gi_pre[(size_t)pair*G3H + j] = acc[r] + bj;
    }
  }
  {
    int d = nq*16 + r16;
    sh8 bf0 = ldfrag(eaW + (size_t)d*KBD + g4*8);
    sh8 bf1 = ldfrag(eaW + (size_t)d*KBD + 32 + g4*8);
    f32x4 acc = {0.f,0.f,0.f,0.f};
    acc = __builtin_amdgcn_mfma_f32_16x16x32_bf16(akb[0], bf0, acc,0,0,0);
    acc = __builtin_amdgcn_mfma_f32_16x16x32_bf16(akb[1], bf1, acc,0,0,0);
    float bd = eab[d];
    #pragma unroll
    for (int r=0;r<4;r++){
      int pair = base + m*16 + g4*4 + r;
      float v = tanhf(acc[r] + bd);
      ea_pre[(size_t)pair*KBD + d] = v;
      int bb = pair/TT, tt = pair - bb*TT;
      ea_bfT[((size_t)bb*64 + d)*64 + tt] = __float2bfloat16(v);
    }
  }
}

// ====== k_scanh: blocks 0-15 = h-recurrence (4 waves); 16-79 = gram ======
__global__ __launch_bounds__(256,2) void k_scanh(
    const float* __restrict__ gi_pre,
    const float* __restrict__ Whh, const float* __restrict__ bhh,
    const float* __restrict__ ea_pre, const float* __restrict__ rmat,
    float* __restrict__ Gg, float* __restrict__ Pg,
    __hip_bfloat16* __restrict__ h_stream) {
  const int tid = threadIdx.x;
  const int w = tid>>6, l = tid&63, r16 = l&15, g4 = l>>4;

  if (blockIdx.x >= 16) {
    const int b = (blockIdx.x-16)*4 + w;
    sh8 aa[4][2];
    #pragma unroll
    for (int i=0;i<4;i++){
      int row = i*16 + r16; if (row > TT-1) row = TT-1;
      #pragma unroll
      for (int f=0;f<2;f++)
        aa[i][f] = ldfrag(ea_pre + ((size_t)b*TT + row)*KBD + f*32 + g4*8);
    }
    sh8 rmB[2];
    #pragma unroll
    for (int f=0;f<2;f++){
      sh8 z = {0,0,0,0,0,0,0,0};
      if (r16 < NF) z = ldfrag(rmat + (size_t)r16*KBD + f*32 + g4*8);
      rmB[f] = z;
    }
    float* Gb = Gg + ((size_t)b<<12);
    #pragma unroll
    for (int i=0;i<4;i++){
      #pragma unroll
      for (int j=0;j<4;j++){
        f32x4 acc={0.f,0.f,0.f,0.f};
        #pragma unroll
        for (int f=0;f<2;f++) acc = __builtin_amdgcn_mfma_f32_16x16x32_bf16(aa[i][f], aa[j][f], acc,0,0,0);
        #pragma unroll
        for (int r=0;r<4;r++) Gb[(i*16+g4*4+r)*64 + j*16+r16] = acc[r];
      }
      f32x4 accp={0.f,0.f,0.f,0.f};
      #pragma unroll
      for (int f=0;f<2;f++) accp = __builtin_amdgcn_mfma_f32_16x16x32_bf16(aa[i][f], rmB[f], accp,0,0,0);
      #pragma unroll
      for (int r=0;r<4;r++) Pg[((size_t)b<<10) + (i*16+g4*4+r)*16 + r16] = accp[r];
    }
    return;
  }

  __shared__ __hip_bfloat16 hcat[2][16][128];
  __builtin_amdgcn_s_setprio(1);
  const int b = blockIdx.x;
  const int b0 = b*16;
  for (int i=tid;i<2*16*128;i+=256) ((short*)hcat)[i]=0;
  __syncthreads();
  const int swz = (r16&7)<<4;

  sh8 whhF[2][3][4];
  #pragma unroll
  for (int t=0;t<2;t++)
    #pragma unroll
    for (int g=0;g<3;g++){
      int chain = (w + 4*t) + 8*g;
      #pragma unroll
      for (int f=0;f<4;f++)
        whhF[t][g][f] = ldfrag(Whh + (size_t)(chain*16 + r16)*HH + f*32 + g4*8);
    }
  float4 bhn[2];
  bhn[0] = *(const float4*)(bhh + 2*HH + w*16 + g4*4);
  bhn[1] = *(const float4*)(bhh + 2*HH + (w+4)*16 + g4*4);
  float h_old[2][4] = {{0.f,0.f,0.f,0.f},{0.f,0.f,0.f,0.f}};
  const float* gi_row = gi_pre + (size_t)(b0+r16)*TT*G3H;
  __hip_bfloat16* hsb = h_stream + (size_t)b*TT*16*HH;

  int cur = 0;
  auto stepfn = [&](int s, float4 (&gi)[2][3], int cu){
    const char* hrow = (const char*)&hcat[cu][r16][0];
    sh8 hb[4];
    #pragma unroll
    for (int f=0;f<4;f++)
      hb[f] = *(const sh8*)(hrow + ((f*64 + g4*16) ^ swz));
    f32x4 aR[2], aZ[2], aN[2];
    #pragma unroll
    for (int t=0;t<2;t++){ f32x4 z={0.f,0.f,0.f,0.f}; aR[t]=z; aZ[t]=z; aN[t]=z; }
    #pragma unroll
    for (int f=0;f<4;f++){
      #pragma unroll
      for (int t=0;t<2;t++){
        aR[t] = __builtin_amdgcn_mfma_f32_16x16x32_bf16(whhF[t][0][f], hb[f], aR[t],0,0,0);
        aZ[t] = __builtin_amdgcn_mfma_f32_16x16x32_bf16(whhF[t][1][f], hb[f], aZ[t],0,0,0);
        aN[t] = __builtin_amdgcn_mfma_f32_16x16x32_bf16(whhF[t][2][f], hb[f], aN[t],0,0,0);
      }
    }
    char* hwrow = (char*)&hcat[cu^1][r16][0];
    #pragma unroll
    for (int t=0;t<2;t++){
      sh4 hp;
      #pragma unroll
      for (int r=0;r<4;r++){
        float rr = sigm(gi[t][0][r] + aR[t][r]);
        float zz = sigm(gi[t][1][r] + aZ[t][r]);
        float nn = tanhf_(gi[t][2][r] + rr*(aN[t][r] + bhn[t][r]));
        h_old[t][r] = (1.f-zz)*nn + zz*h_old[t][r];
        hp[r] = f2bs(h_old[t][r]);
      }
      *(sh4*)(hwrow + (((w+4*t)*32 + g4*8) ^ swz)) = hp;
      *(sh4*)(hsb + ((size_t)s*16 + r16)*HH + (w+4*t)*16 + g4*4) = hp;
    }
    barrier_lds();
  };

  float4 gA[2][3], gB[2][3];
  #pragma unroll
  for (int t=0;t<2;t++)
    #pragma unroll
    for (int g=0;g<3;g++)
      gA[t][g] = *(const float4*)(gi_row + g*128 + (w+4*t)*16 + g4*4);

  for (int s=0;s<TT;s+=2){
    {
      int sg = s+1;
      #pragma unroll
      for (int t=0;t<2;t++)
        #pragma unroll
        for (int g=0;g<3;g++)
          gB[t][g] = *(const float4*)(gi_row + (size_t)sg*G3H + g*128 + (w+4*t)*16 + g4*4);
      stepfn(s, gA, cur);
      cur ^= 1;
    }
    {
      int sg = (s+2<TT)? s+2 : TT-1;
      #pragma unroll
      for (int t=0;t<2;t++)
        #pragma unroll
        for (int g=0;g<3;g++)
          gA[t][g] = *(const float4*)(gi_row + (size_t)sg*G3H + g*128 + (w+4*t)*16 + g4*4);
      stepfn(s+1, gB, cur);
      cur ^= 1;
    }
  }
}

// ====== k_mnac: U+softmax (MFMA) + gate recurrence + AC GEMM, one b per block ======
__global__ __launch_bounds__(640) void k_mnac(
    const float* __restrict__ Gg, const float* __restrict__ Pg,
    const float* __restrict__ rmat,
    const __hip_bfloat16* __restrict__ h_stream,
    const float* __restrict__ uW, const float* __restrict__ ub,
    const __hip_bfloat16* __restrict__ ea_bfT,
    __hip_bfloat16* __restrict__ ac_pre) {
  __shared__ __hip_bfloat16 U_sh[64][72];
  __shared__ float aw_sh[64*16];
  __shared__ float AagL[64*52];
  __shared__ float BagL[64*16];
  const int tid = threadIdx.x;
  const int n = tid>>6, l = tid&63, r16 = l&15, g4 = l>>4;
  const int b = blockIdx.x;
  for (int i=tid;i<64*52;i+=640) AagL[i]=0.f;
  for (int i=tid;i<64*16;i+=640) BagL[i]=0.f;

  const __hip_bfloat16* hsb = h_stream + ((size_t)(b>>4)*TT)*16*HH + (size_t)(b&15)*HH;

  // ---- U = tanh(uW.h + ub) for all 50 t (16 tile-combos over 10 waves) ----
  #pragma unroll
  for (int cc=0; cc<2; cc++){
    int c = n + cc*10;
    if (c < 16){
      int mi = c>>2, ni = c&3;
      int t = mi*16 + r16; int tt = (t<TT)? t : TT-1;
      sh8 hfr[4], wfr[4];
      #pragma unroll
      for (int f=0;f<4;f++){
        hfr[f] = *(const sh8*)(hsb + (size_t)tt*16*HH + f*32 + g4*8);
        wfr[f] = ldfrag(uW + (size_t)(ni*16+r16)*HH + f*32 + g4*8);
      }
      f32x4 acc = {0.f,0.f,0.f,0.f};
      #pragma unroll
      for (int f=0;f<4;f++)
        acc = __builtin_amdgcn_mfma_f32_16x16x32_bf16(wfr[f], hfr[f], acc,0,0,0);
      float4 ubv = *(const float4*)(ub + ni*16 + g4*4);
      #pragma unroll
      for (int r=0;r<4;r++)
        U_sh[mi*16 + r16][ni*16 + g4*4 + r] = __float2bfloat16(tanhf_(acc[r] + ubv[r]));
    }
  }
  __syncthreads();
  // ---- attention logits + softmax (waves 0-3; wave w = t-tile) ----
  if (n < 4){
    sh8 rmF[2];
    #pragma unroll
    for (int f=0;f<2;f++){
      sh8 z = {0,0,0,0,0,0,0,0};
      if (r16 < NF) z = ldfrag(rmat + (size_t)r16*KBD + f*32 + g4*8);
      rmF[f] = z;
    }
    sh8 uf[2];
    #pragma unroll
    for (int f=0;f<2;f++) uf[f] = *(const sh8*)&U_sh[n*16 + r16][f*32 + g4*8];
    f32x4 al={0.f,0.f,0.f,0.f};
    #pragma unroll
    for (int f=0;f<2;f++) al = __builtin_amdgcn_mfma_f32_16x16x32_bf16(rmF[f], uf[f], al,0,0,0);
    float mx = -1e30f;
    #pragma unroll
    for (int r=0;r<4;r++){ if (g4*4+r < NF) mx = fmaxf(mx, al[r]); }
    mx = fmaxf(mx, __shfl_xor(mx,16));
    mx = fmaxf(mx, __shfl_xor(mx,32));
    float av[4]; float ssum=0.f;
    #pragma unroll
    for (int r=0;r<4;r++){ av[r] = (g4*4+r < NF) ? __expf(al[r]-mx) : 0.f; ssum += av[r]; }
    ssum += __shfl_xor(ssum,16); ssum += __shfl_xor(ssum,32);
    float inv = frcp(ssum);
    #pragma unroll
    for (int r=0;r<4;r++){
      int nn = g4*4+r;
      if (nn < NF) aw_sh[(n*16 + r16)*16 + nn] = av[r]*inv;
    }
  }
  __syncthreads();

  // ---- gate recurrence (10 waves = n) ----
  float rv = rmat[n*KBD + l];
  float R = rv*rv;
  R += __shfl_xor(R,1); R += __shfl_xor(R,2); R += __shfl_xor(R,4);
  R += __shfl_xor(R,8); R += __shfl_xor(R,16); R += __shfl_xor(R,32);

  float Pn = (l<TT)? Pg[((size_t)b<<10) + l*16 + n] : 0.f;
  const float* Gb = Gg + ((size_t)b<<12);
  float Grow = Gb[l];
  float d=0.f, w_=0.f, q=1.f;

  for (int t=0;t<TT;t++){
    int tn = (t+1<TT)? t+1 : TT-1;
    float GrowN = Gb[tn*64 + l];
    float dt = __shfl(d, t);
    float g  = sigm(dt);
    float og = 1.f - g;
    float Pt = __shfl(Pn, t);
    float Ets = Grow + Pt + Pn + R;
    d = og*d + g*Ets;
    w_ = (l==t)? g : w_*og;
    q *= og;
    float awt = aw_sh[t*16 + n];
    if (l < TT) atomicAdd(&AagL[t*52 + l], awt*w_);
    if (l == 0) BagL[t*16 + n] = awt*(1.f - q);
    Grow = GrowN;
  }
  __syncthreads();

  // ---- fused AC GEMM (waves 0-3; wave w owns j-tile w) ----
  if (n < 4){
    const int w = n;
    sh8 a1[4][2], a2[4];
    #pragma unroll
    for (int i=0;i<4;i++){
      int row = i*16 + r16;
      #pragma unroll
      for (int f=0;f<2;f++) a1[i][f] = ldfrag(&AagL[row*52 + f*32 + g4*8]);
      a2[i] = ldfrag(&BagL[row*16 + ((g4*8) & 15)]);
      if (g4 >= 2){ sh8 z={0,0,0,0,0,0,0,0}; a2[i]=z; }
    }
    int j = w;
    sh8 bb1[2];
    #pragma unroll
    for (int f=0;f<2;f++)
      bb1[f] = *(const sh8*)(ea_bfT + ((size_t)b<<12) + (j*16+r16)*64 + f*32 + g4*8);
    sh8 bb2;
    #pragma unroll
    for (int c=0;c<8;c++){
      int k = g4*8 + c;
      bb2[c] = (k<NF)? f2bs(rmat[k*KBD + j*16+r16]) : (short)0;
    }
    #pragma unroll
    for (int i=0;i<4;i++){
      f32x4 acc={0.f,0.f,0.f,0.f};
      #pragma unroll
      for (int f=0;f<2;f++) acc = __builtin_amdgcn_mfma_f32_16x16x32_bf16(a1[i][f], bb1[f], acc,0,0,0);
      acc = __builtin_amdgcn_mfma_f32_16x16x32_bf16(a2[i], bb2, acc,0,0,0);
      #pragma unroll
      for (int r=0;r<4;r++){
        int t = i*16 + g4*4 + r;
        if (t < TT)
          ac_pre[((size_t)t*256 + b)*KBD + j*16 + r16] = __float2bfloat16(acc[r]);
      }
    }
  }
}

// ====== k_uty: blocks 0..207 = Ut+y (4 t's each); blocks 208+ = Sy ======
__global__ __launch_bounds__(512) void k_uty(
    const __hip_bfloat16* __restrict__ h_stream, const __hip_bfloat16* __restrict__ ac_pre,
    const float* __restrict__ u2W, const float* __restrict__ u2b,
    const float* __restrict__ m1W, const float* __restrict__ m1b,
    float* __restrict__ ybf32,
    const float* __restrict__ E, const float* __restrict__ KBE,
    const float* __restrict__ m2W, const float* __restrict__ m2b,
    __hip_bfloat16* __restrict__ Sy) {
  __shared__ __hip_bfloat16 ut_sh[2][16][136];
  const int tid = threadIdx.x;
  const int w = tid>>6, l = tid&63, r16 = l&15, g4 = l>>4;

  if (blockIdx.x >= NUTY) {
    // ---------------- Sy path ----------------
    int kof = g4*8;
    sh8 bbf[4][4];
    float bias[4];
    #pragma unroll
    for (int nt=0;nt<4;nt++){
      int o = nt*16 + r16;
      bias[nt] = m2b[o];
      #pragma unroll
      for (int ks=0;ks<4;ks++) bbf[nt][ks] = ldfrag(m2W + o*128 + ks*32 + kof);
    }
    int wid = (blockIdx.x-NUTY)*8 + w;
    for (int tile=wid; tile<NTILE; tile+=NSY*8){
      int v = tile*16 + r16;
      sh8 aa[4];
      const float* ep = E + (size_t)v*EMB + kof;
      const float* kp = KBE + (size_t)v*KBD + kof;
      aa[0] = ldfrag(ep); aa[1] = ldfrag(ep+32);
      aa[2] = ldfrag(kp); aa[3] = ldfrag(kp+32);
      if (v==0){ sh8 z={0,0,0,0,0,0,0,0}; aa[0]=z;aa[1]=z;aa[2]=z;aa[3]=z; }
      f32x4 acc[4];
      #pragma unroll
      for (int nt=0;nt<4;nt++){ f32x4 z={0.f,0.f,0.f,0.f}; acc[nt]=z; }
      #pragma unroll
      for (int nt=0;nt<4;nt++)
        #pragma unroll
        for (int ks=0;ks<4;ks++)
          acc[nt] = __builtin_amdgcn_mfma_f32_16x16x32_bf16(aa[ks],bbf[nt][ks],acc[nt],0,0,0);
      #pragma unroll
      for (int nt=0;nt<4;nt++){
        #pragma unroll
        for (int r=0;r<4;r++){
          int vv = tile*16 + g4*4 + r;
          Sy[(size_t)vv*OUTD + nt*16 + r16] = __float2bfloat16(tanhf_(acc[nt][r] + bias[nt]));
        }
      }
    }
    return;
  }

  const int btile = blockIdx.x & 15, tc = blockIdx.x >> 4;
  const int b0 = btile*16, fb = btile;

  sh8 u2F[6];
  #pragma unroll
  for (int f=0;f<6;f++) u2F[f] = ldfrag(u2W + (size_t)(w*16+r16)*(HH+KBD) + f*32 + g4*8);
  sh8 m1F[4];
  if (w<4){
    #pragma unroll
    for (int f=0;f<4;f++) m1F[f] = ldfrag(m1W + (size_t)(w*16+r16)*HH + f*32 + g4*8);
  }
  float4 u2bv = *(const float4*)(u2b + w*16 + g4*4);
  float4 m1bv = (w<4) ? *(const float4*)(m1b + w*16 + g4*4) : float4{0.f,0.f,0.f,0.f};

  #pragma unroll
  for (int it=0; it<TCH; it++){
    int t = tc*TCH + it;
    if (t >= TT) break;
    const int bu = it & 1;
    const __hip_bfloat16* hp = h_stream + (size_t)((fb*TT + t)*16)*HH;
    const __hip_bfloat16* ap = ac_pre + ((size_t)t*256 + b0)*KBD;
    sh8 cb[6];
    #pragma unroll
    for (int f=0;f<4;f++) cb[f] = *(const sh8*)(hp + r16*HH + f*32 + g4*8);
    #pragma unroll
    for (int f=4;f<6;f++) cb[f] = *(const sh8*)(ap + r16*KBD + (f-4)*32 + g4*8);
    f32x4 at={0.f,0.f,0.f,0.f};
    #pragma unroll
    for (int f=0;f<6;f++) at = __builtin_amdgcn_mfma_f32_16x16x32_bf16(u2F[f], cb[f], at,0,0,0);
    sh4 tp;
    #pragma unroll
    for (int r=0;r<4;r++) tp[r] = f2bs(tanhf_(at[r] + u2bv[r]));
    *(sh4*)&ut_sh[bu][r16][w*16+g4*4] = tp;
    __syncthreads();
    if (w<4){
      sh8 tb[4];
      #pragma unroll
      for (int f=0;f<4;f++) tb[f] = *(const sh8*)&ut_sh[bu][r16][f*32+g4*8];
      f32x4 ay={0.f,0.f,0.f,0.f};
      #pragma unroll
      for (int f=0;f<4;f++) ay = __builtin_amdgcn_mfma_f32_16x16x32_bf16(m1F[f], tb[f], ay,0,0,0);
      #pragma unroll
      for (int r=0;r<4;r++)
        atomicAdd(&ybf32[(size_t)(b0 + r16)*OUTD + w*16 + g4*4 + r], tanhf_(ay[r] + m1bv[r]));
    }
  }
}

// ---------------- final: s = y @ Sy^T, log_softmax ----------------
__global__ __launch_bounds__(256) void k_logits(
    const float* __restrict__ ybf32, const __hip_bfloat16* __restrict__ Sy,
    float* __restrict__ denom, float* __restrict__ out, int pass) {
  __shared__ float dsum[64];
  int lane = threadIdx.x & 63;
  int w = threadIdx.x >> 6;
  int r16 = lane & 15, g4 = lane >> 4;
  int kof = g4 * 8;
  int tbase = blockIdx.x * 16 + w * 4;
  const float SC = 1.0f/TT;
  if (pass==0){
    if (threadIdx.x<64) dsum[threadIdx.x]=0.f;
    __syncthreads();
  }
  sh8 b0[4], b1[4];
  #pragma unroll
  for (int i=0;i<4;i++){
    if (tbase + i < NTILE) {
      const __hip_bfloat16* bp = Sy + ((size_t)((tbase+i)*16 + r16))*OUTD + kof;
      b0[i] = *(const sh8*)bp;
      b1[i] = *(const sh8*)(bp + 32);
    } else {
      sh8 z = {0,0,0,0,0,0,0,0};
      b0[i]=z; b1[i]=z;
    }
  }
  int bg0 = blockIdx.y * 4;
  for (int bgi=0; bgi<4; bgi++){
    int bg = bg0 + bgi;
    const float* ap = ybf32 + (size_t)(bg*16 + r16)*OUTD + kof;
    sh8 a0 = ldfrag_s(ap, SC);
    sh8 a1 = ldfrag_s(ap+32, SC);
    if (pass == 0){
      float part[4] = {0.f,0.f,0.f,0.f};
      #pragma unroll
      for (int i=0;i<4;i++){
        if (tbase + i < NTILE){
          f32x4 acc = {0.f,0.f,0.f,0.f};
          acc = __builtin_amdgcn_mfma_f32_16x16x32_bf16(a0,b0[i],acc,0,0,0);
          acc = __builtin_amdgcn_mfma_f32_16x16x32_bf16(a1,b1[i],acc,0,0,0);
          #pragma unroll
          for (int r=0;r<4;r++) part[r] += __expf(acc[r]);
        }
      }
      #pragma unroll
      for (int r=0;r<4;r++){
        float p = part[r];
        p += __shfl_xor(p,1,16); p += __shfl_xor(p,2,16);
        p += __shfl_xor(p,4,16); p += __shfl_xor(p,8,16);
        if (r16==0) atomicAdd(&dsum[bgi*16 + g4*4 + r], p);
      }
    } else {
      float lse[4];
      #pragma unroll
      for (int r=0;r<4;r++) lse[r] = logf(denom[(size_t)(bg*16 + g4*4 + r)*DSTR]);
      #pragma unroll
      for (int i=0;i<4;i++){
        if (tbase + i < NTILE){
          f32x4 acc = {0.f,0.f,0.f,0.f};
          acc = __builtin_amdgcn_mfma_f32_16x16x32_bf16(a0,b0[i],acc,0,0,0);
          acc = __builtin_amdgcn_mfma_f32_16x16x32_bf16(a1,b1[i],acc,0,0,0);
          int vc = (tbase+i)*16 + r16;
          #pragma unroll
          for (int r=0;r<4;r++)
            out[(size_t)(bg*16 + g4*4 + r)*VV + vc] = acc[r] - lse[r];
        }
      }
    }
  }
  if (pass==0){
    __syncthreads();
    if (threadIdx.x<64)
      atomicAdd(&denom[(size_t)(bg0*16 + threadIdx.x)*DSTR], dsum[threadIdx.x]);
  }
}

extern "C" void kernel_launch(void* const* d_in, const int* in_sizes, int n_in,
                              void* d_out, int out_size, void* d_ws, size_t ws_size,
                              hipStream_t stream) {
  const int*   X    = (const int*)  d_in[0];
  const float* E    = (const float*)d_in[1];
  const float* KBE  = (const float*)d_in[2];
  const float* rmat = (const float*)d_in[3];
  const float* Wih  = (const float*)d_in[4];
  const float* Whh  = (const float*)d_in[5];
  const float* bih  = (const float*)d_in[6];
  const float* bhh  = (const float*)d_in[7];
  const float* uW   = (const float*)d_in[8];
  const float* ub   = (const float*)d_in[9];
  const float* eaW  = (const float*)d_in[10];
  const float* eab  = (const float*)d_in[11];
  const float* u2W  = (const float*)d_in[12];
  const float* u2b  = (const float*)d_in[13];
  const float* m1W  = (const float*)d_in[14];
  const float* m1b  = (const float*)d_in[15];
  const float* m2W  = (const float*)d_in[16];
  const float* m2b  = (const float*)d_in[17];
  float* outp = (float*)d_out;

  char* p = (char*)d_ws;
  float* gi_pre = (float*)p;            p += (size_t)BB*TT*G3H*4;
  float* ea_pre = (float*)p;            p += (size_t)BB*TT*KBD*4;
  float* denom  = (float*)p;            p += (size_t)BB*DSTR*4;
  float* ybf32  = (float*)p;            p += (size_t)BB*OUTD*4;
  float* Gg     = (float*)p;            p += (size_t)BB*64*64*4;
  float* Pg     = (float*)p;            p += (size_t)BB*64*16*4;
  __hip_bfloat16* h_stream = (__hip_bfloat16*)p; p += (size_t)16*TT*16*HH*2;
  __hip_bfloat16* ea_bfT = (__hip_bfloat16*)p;   p += (size_t)BB*64*64*2;
  __hip_bfloat16* ac_pre = (__hip_bfloat16*)p;   p += (size_t)BB*TT*KBD*2;
  __hip_bfloat16* Sy     = (__hip_bfloat16*)p;   p += (size_t)VV*OUTD*2;

  k_pre<<<400,512,0,stream>>>(X,E,KBE,Wih,bih,bhh,eaW,eab,gi_pre,ea_pre,ea_bfT,denom,ybf32);
  k_scanh<<<80,256,0,stream>>>(gi_pre,Whh,bhh,ea_pre,rmat,Gg,Pg,h_stream);
  k_mnac<<<256,640,0,stream>>>(Gg,Pg,rmat,h_stream,uW,ub,ea_bfT,ac_pre);
  k_uty<<<NUTY+NSY,512,0,stream>>>(h_stream,ac_pre,u2W,u2b,m1W,m1b,ybf32,
                                   E,KBE,m2W,m2b,Sy);
  dim3 g1((NTILE + 15)/16, 4, 1);
  k_logits<<<g1,256,0,stream>>>(ybf32,Sy,denom,outp,0);
  k_logits<<<g1,256,0,stream>>>(ybf32,Sy,denom,outp,1);
}

// Round 17
// 219.508 us; speedup vs baseline: 1.0636x; 1.0248x over previous
//
#include <hip/hip_runtime.h>
#include <hip/hip_bf16.h>
#include <math.h>

#define BB 256
#define TT 50
#define VV 100000
#define EMB 64
#define KBD 64
#define HH 128
#define NF 10
#define OUTD 64
#define G3H 384
#define NTILE 6250   // VV/16
#define DSTR 16      // denom stride (floats)
#define NSY 240      // Sy blocks (folded into k_scanh launch, 4 waves each)
#define TCH 4        // t's per k_uty block
#define NUTY (16*13) // 16 btiles x ceil(50/4)=13 tchunks

typedef __attribute__((ext_vector_type(8))) short sh8;
typedef __attribute__((ext_vector_type(4))) short sh4;
typedef __attribute__((ext_vector_type(4))) float f32x4;

__device__ __forceinline__ float frcp(float x){ return __builtin_amdgcn_rcpf(x); }
__device__ __forceinline__ float sigm(float x){ return frcp(1.0f+__expf(-x)); }
__device__ __forceinline__ float tanhf_(float x){ return 1.0f - 2.0f*frcp(__expf(2.0f*x)+1.0f); }
__device__ __forceinline__ short f2bs(float f){ __hip_bfloat16 h=__float2bfloat16(f); return *reinterpret_cast<short*>(&h); }
__device__ __forceinline__ sh8 ldfrag(const float* p){
  float4 a = *(const float4*)p; float4 b = *(const float4*)(p+4);
  sh8 v;
  v[0]=f2bs(a.x); v[1]=f2bs(a.y); v[2]=f2bs(a.z); v[3]=f2bs(a.w);
  v[4]=f2bs(b.x); v[5]=f2bs(b.y); v[6]=f2bs(b.z); v[7]=f2bs(b.w);
  return v;
}
__device__ __forceinline__ sh8 ldfrag_s(const float* p, float s){
  float4 a = *(const float4*)p; float4 b = *(const float4*)(p+4);
  sh8 v;
  v[0]=f2bs(a.x*s); v[1]=f2bs(a.y*s); v[2]=f2bs(a.z*s); v[3]=f2bs(a.w*s);
  v[4]=f2bs(b.x*s); v[5]=f2bs(b.y*s); v[6]=f2bs(b.z*s); v[7]=f2bs(b.w*s);
  return v;
}
// LDS-only barrier (no vmcnt drain)
__device__ __forceinline__ void barrier_lds(){
  asm volatile("s_waitcnt lgkmcnt(0)" ::: "memory");
  __builtin_amdgcn_sched_barrier(0);
  __builtin_amdgcn_s_barrier();
  __builtin_amdgcn_sched_barrier(0);
}

// ====== k_pre: gi/ea via MFMA (400 blocks); block 0 zeros denom + ybf32 ======
#define PREP 32
__global__ __launch_bounds__(512) void k_pre(
    const int* __restrict__ X, const float* __restrict__ E, const float* __restrict__ KBE,
    const float* __restrict__ Wih, const float* __restrict__ bih, const float* __restrict__ bhh,
    const float* __restrict__ eaW, const float* __restrict__ eab,
    float* __restrict__ gi_pre, float* __restrict__ ea_pre,
    __hip_bfloat16* __restrict__ ea_bfT, float* __restrict__ denom,
    float* __restrict__ ybf32) {
  const int tid = threadIdx.x;
  const int w = tid>>6, l = tid&63, r16 = l&15, g4 = l>>4;

  if (blockIdx.x == 0){
    for (int i=tid;i<BB*DSTR;i+=512) denom[i]=0.f;
    for (int i=tid;i<BB*OUTD;i+=512) ybf32[i]=0.f;
  }
  __shared__ float xeL[PREP][68];
  __shared__ float kbL[PREP][68];
  int base = blockIdx.x * PREP;
  for (int i=tid; i<PREP*EMB; i+=512){
    int p=i>>6, k=i&63; int x = X[base+p];
    xeL[p][k] = x ? E[(size_t)x*EMB+k] : 0.0f;
    kbL[p][k] = x ? KBE[(size_t)x*KBD+k] : 0.0f;
  }
  __syncthreads();

  const int m = w>>2, nq = w&3;
  sh8 axe[2], akb[2];
  #pragma unroll
  for (int f=0;f<2;f++){
    axe[f] = ldfrag(&xeL[m*16 + r16][f*32 + g4*8]);
    akb[f] = ldfrag(&kbL[m*16 + r16][f*32 + g4*8]);
  }
  #pragma unroll
  for (int i=0;i<6;i++){
    int nt = nq*6 + i;
    int j = nt*16 + r16;
    sh8 bf0 = ldfrag(Wih + (size_t)j*EMB + g4*8);
    sh8 bf1 = ldfrag(Wih + (size_t)j*EMB + 32 + g4*8);
    f32x4 acc = {0.f,0.f,0.f,0.f};
    acc = __builtin_amdgcn_mfma_f32_16x16x32_bf16(axe[0], bf0, acc,0,0,0);
    acc = __builtin_amdgcn_mfma_f32_16x16x32_bf16(axe[1], bf1, acc,0,0,0);
    float bj = bih[j] + (j < 2*HH ? bhh[j] : 0.0f);
    #pragma unroll
    for (int r=0;r<4;r++){
      int pair = base + m*16 + g4*4 + r;
      gi_pre[(size_t)pair*G3H + j] = acc[r] + bj;
    }
  }
  {
    int d = nq*16 + r16;
    sh8 bf0 = ldfrag(eaW + (size_t)d*KBD + g4*8);
    sh8 bf1 = ldfrag(eaW + (size_t)d*KBD + 32 + g4*8);
    f32x4 acc = {0.f,0.f,0.f,0.f};
    acc = __builtin_amdgcn_mfma_f32_16x16x32_bf16(akb[0], bf0, acc,0,0,0);
    acc = __builtin_amdgcn_mfma_f32_16x16x32_bf16(akb[1], bf1, acc,0,0,0);
    float bd = eab[d];
    #pragma unroll
    for (int r=0;r<4;r++){
      int pair = base + m*16 + g4*4 + r;
      float v = tanhf(acc[r] + bd);
      ea_pre[(size_t)pair*KBD + d] = v;
      int bb = pair/TT, tt = pair - bb*TT;
      ea_bfT[((size_t)bb*64 + d)*64 + tt] = __float2bfloat16(v);
    }
  }
}

// ====== k_scanh: 0-15 h-recurrence; 16-79 gram; 80-319 Sy (4 waves) ======
__global__ __launch_bounds__(256,2) void k_scanh(
    const float* __restrict__ gi_pre,
    const float* __restrict__ Whh, const float* __restrict__ bhh,
    const float* __restrict__ ea_pre, const float* __restrict__ rmat,
    float* __restrict__ Gg, float* __restrict__ Pg,
    __hip_bfloat16* __restrict__ h_stream,
    const float* __restrict__ E, const float* __restrict__ KBE,
    const float* __restrict__ m2W, const float* __restrict__ m2b,
    __hip_bfloat16* __restrict__ Sy) {
  const int tid = threadIdx.x;
  const int w = tid>>6, l = tid&63, r16 = l&15, g4 = l>>4;

  if (blockIdx.x >= 80) {
    // ---------------- Sy path (4 waves/block, 240 blocks) ----------------
    int kof = g4*8;
    sh8 bbf[4][4];
    float bias[4];
    #pragma unroll
    for (int nt=0;nt<4;nt++){
      int o = nt*16 + r16;
      bias[nt] = m2b[o];
      #pragma unroll
      for (int ks=0;ks<4;ks++) bbf[nt][ks] = ldfrag(m2W + o*128 + ks*32 + kof);
    }
    int wid = (blockIdx.x-80)*4 + w;
    for (int tile=wid; tile<NTILE; tile+=NSY*4){
      int v = tile*16 + r16;
      sh8 aa[4];
      const float* ep = E + (size_t)v*EMB + kof;
      const float* kp = KBE + (size_t)v*KBD + kof;
      aa[0] = ldfrag(ep); aa[1] = ldfrag(ep+32);
      aa[2] = ldfrag(kp); aa[3] = ldfrag(kp+32);
      if (v==0){ sh8 z={0,0,0,0,0,0,0,0}; aa[0]=z;aa[1]=z;aa[2]=z;aa[3]=z; }
      f32x4 acc[4];
      #pragma unroll
      for (int nt=0;nt<4;nt++){ f32x4 z={0.f,0.f,0.f,0.f}; acc[nt]=z; }
      #pragma unroll
      for (int nt=0;nt<4;nt++)
        #pragma unroll
        for (int ks=0;ks<4;ks++)
          acc[nt] = __builtin_amdgcn_mfma_f32_16x16x32_bf16(aa[ks],bbf[nt][ks],acc[nt],0,0,0);
      #pragma unroll
      for (int nt=0;nt<4;nt++){
        #pragma unroll
        for (int r=0;r<4;r++){
          int vv = tile*16 + g4*4 + r;
          Sy[(size_t)vv*OUTD + nt*16 + r16] = __float2bfloat16(tanhf_(acc[nt][r] + bias[nt]));
        }
      }
    }
    return;
  }

  if (blockIdx.x >= 16) {
    const int b = (blockIdx.x-16)*4 + w;
    sh8 aa[4][2];
    #pragma unroll
    for (int i=0;i<4;i++){
      int row = i*16 + r16; if (row > TT-1) row = TT-1;
      #pragma unroll
      for (int f=0;f<2;f++)
        aa[i][f] = ldfrag(ea_pre + ((size_t)b*TT + row)*KBD + f*32 + g4*8);
    }
    sh8 rmB[2];
    #pragma unroll
    for (int f=0;f<2;f++){
      sh8 z = {0,0,0,0,0,0,0,0};
      if (r16 < NF) z = ldfrag(rmat + (size_t)r16*KBD + f*32 + g4*8);
      rmB[f] = z;
    }
    float* Gb = Gg + ((size_t)b<<12);
    #pragma unroll
    for (int i=0;i<4;i++){
      #pragma unroll
      for (int j=0;j<4;j++){
        f32x4 acc={0.f,0.f,0.f,0.f};
        #pragma unroll
        for (int f=0;f<2;f++) acc = __builtin_amdgcn_mfma_f32_16x16x32_bf16(aa[i][f], aa[j][f], acc,0,0,0);
        #pragma unroll
        for (int r=0;r<4;r++) Gb[(i*16+g4*4+r)*64 + j*16+r16] = acc[r];
      }
      f32x4 accp={0.f,0.f,0.f,0.f};
      #pragma unroll
      for (int f=0;f<2;f++) accp = __builtin_amdgcn_mfma_f32_16x16x32_bf16(aa[i][f], rmB[f], accp,0,0,0);
      #pragma unroll
      for (int r=0;r<4;r++) Pg[((size_t)b<<10) + (i*16+g4*4+r)*16 + r16] = accp[r];
    }
    return;
  }

  __shared__ __hip_bfloat16 hcat[2][16][128];
  __builtin_amdgcn_s_setprio(1);
  const int b = blockIdx.x;
  const int b0 = b*16;
  for (int i=tid;i<2*16*128;i+=256) ((short*)hcat)[i]=0;
  __syncthreads();
  const int swz = (r16&7)<<4;

  sh8 whhF[2][3][4];
  #pragma unroll
  for (int t=0;t<2;t++)
    #pragma unroll
    for (int g=0;g<3;g++){
      int chain = (w + 4*t) + 8*g;
      #pragma unroll
      for (int f=0;f<4;f++)
        whhF[t][g][f] = ldfrag(Whh + (size_t)(chain*16 + r16)*HH + f*32 + g4*8);
    }
  float4 bhn[2];
  bhn[0] = *(const float4*)(bhh + 2*HH + w*16 + g4*4);
  bhn[1] = *(const float4*)(bhh + 2*HH + (w+4)*16 + g4*4);
  float h_old[2][4] = {{0.f,0.f,0.f,0.f},{0.f,0.f,0.f,0.f}};
  const float* gi_row = gi_pre + (size_t)(b0+r16)*TT*G3H;
  __hip_bfloat16* hsb = h_stream + (size_t)b*TT*16*HH;

  int cur = 0;
  auto stepfn = [&](int s, float4 (&gi)[2][3], int cu){
    const char* hrow = (const char*)&hcat[cu][r16][0];
    sh8 hb[4];
    #pragma unroll
    for (int f=0;f<4;f++)
      hb[f] = *(const sh8*)(hrow + ((f*64 + g4*16) ^ swz));
    f32x4 aR[2], aZ[2], aN[2];
    #pragma unroll
    for (int t=0;t<2;t++){ f32x4 z={0.f,0.f,0.f,0.f}; aR[t]=z; aZ[t]=z; aN[t]=z; }
    #pragma unroll
    for (int f=0;f<4;f++){
      #pragma unroll
      for (int t=0;t<2;t++){
        aR[t] = __builtin_amdgcn_mfma_f32_16x16x32_bf16(whhF[t][0][f], hb[f], aR[t],0,0,0);
        aZ[t] = __builtin_amdgcn_mfma_f32_16x16x32_bf16(whhF[t][1][f], hb[f], aZ[t],0,0,0);
        aN[t] = __builtin_amdgcn_mfma_f32_16x16x32_bf16(whhF[t][2][f], hb[f], aN[t],0,0,0);
      }
    }
    char* hwrow = (char*)&hcat[cu^1][r16][0];
    #pragma unroll
    for (int t=0;t<2;t++){
      sh4 hp;
      #pragma unroll
      for (int r=0;r<4;r++){
        float rr = sigm(gi[t][0][r] + aR[t][r]);
        float zz = sigm(gi[t][1][r] + aZ[t][r]);
        float nn = tanhf_(gi[t][2][r] + rr*(aN[t][r] + bhn[t][r]));
        h_old[t][r] = (1.f-zz)*nn + zz*h_old[t][r];
        hp[r] = f2bs(h_old[t][r]);
      }
      *(sh4*)(hwrow + (((w+4*t)*32 + g4*8) ^ swz)) = hp;
      *(sh4*)(hsb + ((size_t)s*16 + r16)*HH + (w+4*t)*16 + g4*4) = hp;
    }
    barrier_lds();
  };

  float4 gA[2][3], gB[2][3];
  #pragma unroll
  for (int t=0;t<2;t++)
    #pragma unroll
    for (int g=0;g<3;g++)
      gA[t][g] = *(const float4*)(gi_row + g*128 + (w+4*t)*16 + g4*4);

  for (int s=0;s<TT;s+=2){
    {
      int sg = s+1;
      #pragma unroll
      for (int t=0;t<2;t++)
        #pragma unroll
        for (int g=0;g<3;g++)
          gB[t][g] = *(const float4*)(gi_row + (size_t)sg*G3H + g*128 + (w+4*t)*16 + g4*4);
      stepfn(s, gA, cur);
      cur ^= 1;
    }
    {
      int sg = (s+2<TT)? s+2 : TT-1;
      #pragma unroll
      for (int t=0;t<2;t++)
        #pragma unroll
        for (int g=0;g<3;g++)
          gA[t][g] = *(const float4*)(gi_row + (size_t)sg*G3H + g*128 + (w+4*t)*16 + g4*4);
      stepfn(s+1, gB, cur);
      cur ^= 1;
    }
  }
}

// ====== k_mnac: U+softmax (MFMA) + gate recurrence + AC GEMM, one b per block ======
__global__ __launch_bounds__(640) void k_mnac(
    const float* __restrict__ Gg, const float* __restrict__ Pg,
    const float* __restrict__ rmat,
    const __hip_bfloat16* __restrict__ h_stream,
    const float* __restrict__ uW, const float* __restrict__ ub,
    const __hip_bfloat16* __restrict__ ea_bfT,
    __hip_bfloat16* __restrict__ ac_pre) {
  __shared__ __hip_bfloat16 U_sh[64][72];
  __shared__ float aw_sh[64*16];
  __shared__ float AagL[64*52];
  __shared__ float BagL[64*16];
  const int tid = threadIdx.x;
  const int n = tid>>6, l = tid&63, r16 = l&15, g4 = l>>4;
  const int b = blockIdx.x;
  for (int i=tid;i<64*52;i+=640) AagL[i]=0.f;
  for (int i=tid;i<64*16;i+=640) BagL[i]=0.f;

  const __hip_bfloat16* hsb = h_stream + ((size_t)(b>>4)*TT)*16*HH + (size_t)(b&15)*HH;

  // ---- U = tanh(uW.h + ub) for all 50 t (16 tile-combos over 10 waves) ----
  #pragma unroll
  for (int cc=0; cc<2; cc++){
    int c = n + cc*10;
    if (c < 16){
      int mi = c>>2, ni = c&3;
      int t = mi*16 + r16; int tt = (t<TT)? t : TT-1;
      sh8 hfr[4], wfr[4];
      #pragma unroll
      for (int f=0;f<4;f++){
        hfr[f] = *(const sh8*)(hsb + (size_t)tt*16*HH + f*32 + g4*8);
        wfr[f] = ldfrag(uW + (size_t)(ni*16+r16)*HH + f*32 + g4*8);
      }
      f32x4 acc = {0.f,0.f,0.f,0.f};
      #pragma unroll
      for (int f=0;f<4;f++)
        acc = __builtin_amdgcn_mfma_f32_16x16x32_bf16(wfr[f], hfr[f], acc,0,0,0);
      float4 ubv = *(const float4*)(ub + ni*16 + g4*4);
      #pragma unroll
      for (int r=0;r<4;r++)
        U_sh[mi*16 + r16][ni*16 + g4*4 + r] = __float2bfloat16(tanhf_(acc[r] + ubv[r]));
    }
  }
  __syncthreads();
  // ---- attention logits + softmax (waves 0-3; wave w = t-tile) ----
  if (n < 4){
    sh8 rmF[2];
    #pragma unroll
    for (int f=0;f<2;f++){
      sh8 z = {0,0,0,0,0,0,0,0};
      if (r16 < NF) z = ldfrag(rmat + (size_t)r16*KBD + f*32 + g4*8);
      rmF[f] = z;
    }
    sh8 uf[2];
    #pragma unroll
    for (int f=0;f<2;f++) uf[f] = *(const sh8*)&U_sh[n*16 + r16][f*32 + g4*8];
    f32x4 al={0.f,0.f,0.f,0.f};
    #pragma unroll
    for (int f=0;f<2;f++) al = __builtin_amdgcn_mfma_f32_16x16x32_bf16(rmF[f], uf[f], al,0,0,0);
    float mx = -1e30f;
    #pragma unroll
    for (int r=0;r<4;r++){ if (g4*4+r < NF) mx = fmaxf(mx, al[r]); }
    mx = fmaxf(mx, __shfl_xor(mx,16));
    mx = fmaxf(mx, __shfl_xor(mx,32));
    float av[4]; float ssum=0.f;
    #pragma unroll
    for (int r=0;r<4;r++){ av[r] = (g4*4+r < NF) ? __expf(al[r]-mx) : 0.f; ssum += av[r]; }
    ssum += __shfl_xor(ssum,16); ssum += __shfl_xor(ssum,32);
    float inv = frcp(ssum);
    #pragma unroll
    for (int r=0;r<4;r++){
      int nn = g4*4+r;
      if (nn < NF) aw_sh[(n*16 + r16)*16 + nn] = av[r]*inv;
    }
  }
  __syncthreads();

  // ---- gate recurrence (10 waves = n) ----
  float rv = rmat[n*KBD + l];
  float R = rv*rv;
  R += __shfl_xor(R,1); R += __shfl_xor(R,2); R += __shfl_xor(R,4);
  R += __shfl_xor(R,8); R += __shfl_xor(R,16); R += __shfl_xor(R,32);

  float Pn = (l<TT)? Pg[((size_t)b<<10) + l*16 + n] : 0.f;
  const float* Gb = Gg + ((size_t)b<<12);
  float Grow = Gb[l];
  float d=0.f, w_=0.f, q=1.f;

  for (int t=0;t<TT;t++){
    int tn = (t+1<TT)? t+1 : TT-1;
    float GrowN = Gb[tn*64 + l];
    float dt = __shfl(d, t);
    float g  = sigm(dt);
    float og = 1.f - g;
    float Pt = __shfl(Pn, t);
    float Ets = Grow + Pt + Pn + R;
    d = og*d + g*Ets;
    w_ = (l==t)? g : w_*og;
    q *= og;
    float awt = aw_sh[t*16 + n];
    if (l < TT) atomicAdd(&AagL[t*52 + l], awt*w_);
    if (l == 0) BagL[t*16 + n] = awt*(1.f - q);
    Grow = GrowN;
  }
  __syncthreads();

  // ---- fused AC GEMM (waves 0-3; wave w owns j-tile w) ----
  if (n < 4){
    const int w = n;
    sh8 a1[4][2], a2[4];
    #pragma unroll
    for (int i=0;i<4;i++){
      int row = i*16 + r16;
      #pragma unroll
      for (int f=0;f<2;f++) a1[i][f] = ldfrag(&AagL[row*52 + f*32 + g4*8]);
      a2[i] = ldfrag(&BagL[row*16 + ((g4*8) & 15)]);
      if (g4 >= 2){ sh8 z={0,0,0,0,0,0,0,0}; a2[i]=z; }
    }
    int j = w;
    sh8 bb1[2];
    #pragma unroll
    for (int f=0;f<2;f++)
      bb1[f] = *(const sh8*)(ea_bfT + ((size_t)b<<12) + (j*16+r16)*64 + f*32 + g4*8);
    sh8 bb2;
    #pragma unroll
    for (int c=0;c<8;c++){
      int k = g4*8 + c;
      bb2[c] = (k<NF)? f2bs(rmat[k*KBD + j*16+r16]) : (short)0;
    }
    #pragma unroll
    for (int i=0;i<4;i++){
      f32x4 acc={0.f,0.f,0.f,0.f};
      #pragma unroll
      for (int f=0;f<2;f++) acc = __builtin_amdgcn_mfma_f32_16x16x32_bf16(a1[i][f], bb1[f], acc,0,0,0);
      acc = __builtin_amdgcn_mfma_f32_16x16x32_bf16(a2[i], bb2, acc,0,0,0);
      #pragma unroll
      for (int r=0;r<4;r++){
        int t = i*16 + g4*4 + r;
        if (t < TT)
          ac_pre[((size_t)t*256 + b)*KBD + j*16 + r16] = __float2bfloat16(acc[r]);
      }
    }
  }
}

// ====== k_uty: 208 blocks = Ut+y (4 t's each) ======
__global__ __launch_bounds__(512) void k_uty(
    const __hip_bfloat16* __restrict__ h_stream, const __hip_bfloat16* __restrict__ ac_pre,
    const float* __restrict__ u2W, const float* __restrict__ u2b,
    const float* __restrict__ m1W, const float* __restrict__ m1b,
    float* __restrict__ ybf32) {
  __shared__ __hip_bfloat16 ut_sh[2][16][136];
  const int tid = threadIdx.x;
  const int w = tid>>6, l = tid&63, r16 = l&15, g4 = l>>4;

  const int btile = blockIdx.x & 15, tc = blockIdx.x >> 4;
  const int b0 = btile*16, fb = btile;

  sh8 u2F[6];
  #pragma unroll
  for (int f=0;f<6;f++) u2F[f] = ldfrag(u2W + (size_t)(w*16+r16)*(HH+KBD) + f*32 + g4*8);
  sh8 m1F[4];
  if (w<4){
    #pragma unroll
    for (int f=0;f<4;f++) m1F[f] = ldfrag(m1W + (size_t)(w*16+r16)*HH + f*32 + g4*8);
  }
  float4 u2bv = *(const float4*)(u2b + w*16 + g4*4);
  float4 m1bv = (w<4) ? *(const float4*)(m1b + w*16 + g4*4) : float4{0.f,0.f,0.f,0.f};

  #pragma unroll
  for (int it=0; it<TCH; it++){
    int t = tc*TCH + it;
    if (t >= TT) break;
    const int bu = it & 1;
    const __hip_bfloat16* hp = h_stream + (size_t)((fb*TT + t)*16)*HH;
    const __hip_bfloat16* ap = ac_pre + ((size_t)t*256 + b0)*KBD;
    sh8 cb[6];
    #pragma unroll
    for (int f=0;f<4;f++) cb[f] = *(const sh8*)(hp + r16*HH + f*32 + g4*8);
    #pragma unroll
    for (int f=4;f<6;f++) cb[f] = *(const sh8*)(ap + r16*KBD + (f-4)*32 + g4*8);
    f32x4 at={0.f,0.f,0.f,0.f};
    #pragma unroll
    for (int f=0;f<6;f++) at = __builtin_amdgcn_mfma_f32_16x16x32_bf16(u2F[f], cb[f], at,0,0,0);
    sh4 tp;
    #pragma unroll
    for (int r=0;r<4;r++) tp[r] = f2bs(tanhf_(at[r] + u2bv[r]));
    *(sh4*)&ut_sh[bu][r16][w*16+g4*4] = tp;
    __syncthreads();
    if (w<4){
      sh8 tb[4];
      #pragma unroll
      for (int f=0;f<4;f++) tb[f] = *(const sh8*)&ut_sh[bu][r16][f*32+g4*8];
      f32x4 ay={0.f,0.f,0.f,0.f};
      #pragma unroll
      for (int f=0;f<4;f++) ay = __builtin_amdgcn_mfma_f32_16x16x32_bf16(m1F[f], tb[f], ay,0,0,0);
      #pragma unroll
      for (int r=0;r<4;r++)
        atomicAdd(&ybf32[(size_t)(b0 + r16)*OUTD + w*16 + g4*4 + r], tanhf_(ay[r] + m1bv[r]));
    }
  }
}

// ---------------- final: s = y @ Sy^T, log_softmax ----------------
__global__ __launch_bounds__(256) void k_logits(
    const float* __restrict__ ybf32, const __hip_bfloat16* __restrict__ Sy,
    float* __restrict__ denom, float* __restrict__ out, int pass) {
  __shared__ float dsum[64];
  int lane = threadIdx.x & 63;
  int w = threadIdx.x >> 6;
  int r16 = lane & 15, g4 = lane >> 4;
  int kof = g4 * 8;
  int tbase = blockIdx.x * 16 + w * 4;
  const float SC = 1.0f/TT;
  if (pass==0){
    if (threadIdx.x<64) dsum[threadIdx.x]=0.f;
    __syncthreads();
  }
  sh8 b0[4], b1[4];
  #pragma unroll
  for (int i=0;i<4;i++){
    if (tbase + i < NTILE) {
      const __hip_bfloat16* bp = Sy + ((size_t)((tbase+i)*16 + r16))*OUTD + kof;
      b0[i] = *(const sh8*)bp;
      b1[i] = *(const sh8*)(bp + 32);
    } else {
      sh8 z = {0,0,0,0,0,0,0,0};
      b0[i]=z; b1[i]=z;
    }
  }
  int bg0 = blockIdx.y * 4;
  for (int bgi=0; bgi<4; bgi++){
    int bg = bg0 + bgi;
    const float* ap = ybf32 + (size_t)(bg*16 + r16)*OUTD + kof;
    sh8 a0 = ldfrag_s(ap, SC);
    sh8 a1 = ldfrag_s(ap+32, SC);
    if (pass == 0){
      float part[4] = {0.f,0.f,0.f,0.f};
      #pragma unroll
      for (int i=0;i<4;i++){
        if (tbase + i < NTILE){
          f32x4 acc = {0.f,0.f,0.f,0.f};
          acc = __builtin_amdgcn_mfma_f32_16x16x32_bf16(a0,b0[i],acc,0,0,0);
          acc = __builtin_amdgcn_mfma_f32_16x16x32_bf16(a1,b1[i],acc,0,0,0);
          #pragma unroll
          for (int r=0;r<4;r++) part[r] += __expf(acc[r]);
        }
      }
      #pragma unroll
      for (int r=0;r<4;r++){
        float p = part[r];
        p += __shfl_xor(p,1,16); p += __shfl_xor(p,2,16);
        p += __shfl_xor(p,4,16); p += __shfl_xor(p,8,16);
        if (r16==0) atomicAdd(&dsum[bgi*16 + g4*4 + r], p);
      }
    } else {
      float lse[4];
      #pragma unroll
      for (int r=0;r<4;r++) lse[r] = logf(denom[(size_t)(bg*16 + g4*4 + r)*DSTR]);
      #pragma unroll
      for (int i=0;i<4;i++){
        if (tbase + i < NTILE){
          f32x4 acc = {0.f,0.f,0.f,0.f};
          acc = __builtin_amdgcn_mfma_f32_16x16x32_bf16(a0,b0[i],acc,0,0,0);
          acc = __builtin_amdgcn_mfma_f32_16x16x32_bf16(a1,b1[i],acc,0,0,0);
          int vc = (tbase+i)*16 + r16;
          #pragma unroll
          for (int r=0;r<4;r++)
            out[(size_t)(bg*16 + g4*4 + r)*VV + vc] = acc[r] - lse[r];
        }
      }
    }
  }
  if (pass==0){
    __syncthreads();
    if (threadIdx.x<64)
      atomicAdd(&denom[(size_t)(bg0*16 + threadIdx.x)*DSTR], dsum[threadIdx.x]);
  }
}

extern "C" void kernel_launch(void* const* d_in, const int* in_sizes, int n_in,
                              void* d_out, int out_size, void* d_ws, size_t ws_size,
                              hipStream_t stream) {
  const int*   X    = (const int*)  d_in[0];
  const float* E    = (const float*)d_in[1];
  const float* KBE  = (const float*)d_in[2];
  const float* rmat = (const float*)d_in[3];
  const float* Wih  = (const float*)d_in[4];
  const float* Whh  = (const float*)d_in[5];
  const float* bih  = (const float*)d_in[6];
  const float* bhh  = (const float*)d_in[7];
  const float* uW   = (const float*)d_in[8];
  const float* ub   = (const float*)d_in[9];
  const float* eaW  = (const float*)d_in[10];
  const float* eab  = (const float*)d_in[11];
  const float* u2W  = (const float*)d_in[12];
  const float* u2b  = (const float*)d_in[13];
  const float* m1W  = (const float*)d_in[14];
  const float* m1b  = (const float*)d_in[15];
  const float* m2W  = (const float*)d_in[16];
  const float* m2b  = (const float*)d_in[17];
  float* outp = (float*)d_out;

  char* p = (char*)d_ws;
  float* gi_pre = (float*)p;            p += (size_t)BB*TT*G3H*4;
  float* ea_pre = (float*)p;            p += (size_t)BB*TT*KBD*4;
  float* denom  = (float*)p;            p += (size_t)BB*DSTR*4;
  float* ybf32  = (float*)p;            p += (size_t)BB*OUTD*4;
  float* Gg     = (float*)p;            p += (size_t)BB*64*64*4;
  float* Pg     = (float*)p;            p += (size_t)BB*64*16*4;
  __hip_bfloat16* h_stream = (__hip_bfloat16*)p; p += (size_t)16*TT*16*HH*2;
  __hip_bfloat16* ea_bfT = (__hip_bfloat16*)p;   p += (size_t)BB*64*64*2;
  __hip_bfloat16* ac_pre = (__hip_bfloat16*)p;   p += (size_t)BB*TT*KBD*2;
  __hip_bfloat16* Sy     = (__hip_bfloat16*)p;   p += (size_t)VV*OUTD*2;

  k_pre<<<400,512,0,stream>>>(X,E,KBE,Wih,bih,bhh,eaW,eab,gi_pre,ea_pre,ea_bfT,denom,ybf32);
  k_scanh<<<80+NSY,256,0,stream>>>(gi_pre,Whh,bhh,ea_pre,rmat,Gg,Pg,h_stream,
                                   E,KBE,m2W,m2b,Sy);
  k_mnac<<<256,640,0,stream>>>(Gg,Pg,rmat,h_stream,uW,ub,ea_bfT,ac_pre);
  k_uty<<<NUTY,512,0,stream>>>(h_stream,ac_pre,u2W,u2b,m1W,m1b,ybf32);
  dim3 g1((NTILE + 15)/16, 4, 1);
  k_logits<<<g1,256,0,stream>>>(ybf32,Sy,denom,outp,0);
  k_logits<<<g1,256,0,stream>>>(ybf32,Sy,denom,outp,1);
}